// Round 2
// baseline (645.948 us; speedup 1.0000x reference)
//
#include <hip/hip_runtime.h>
#include <hip/hip_bf16.h>

// RNN-T joiner: out[b,t,u,v] = sum_k relu(x[b,t,k]+y[b,u,k]) * W[v,k] + bias[v]
// GEMM view: M=131072, N=1024, K=512; A generated on the fly.
//
// Round-2 structure:
//  - BM=64 (one (b,t), all 64 u). A=relu(x+y) staged ONCE per block as bf16
//    into 64KB LDS (XOR-swizzled), then reused across all 8 N-tiles.
//  - W pre-converted to bf16 in d_ws by a prep kernel; B-fragments streamed
//    straight into registers from L2 (1MB, L2-resident) -> NO barriers in the
//    main loop, no per-tile W staging VALU.
//  - 512 threads = 8 waves (2M x 4N), wave tile 32x32, mfma_f32_16x16x32_bf16.
//  - Epilogue per N-tile: nf-innermost store order so both 64B halves of each
//    128B line are adjacent; nontemporal stores (output never re-read).

constexpr int Bc = 8, Tc = 256, Uc = 64, Dc = 512, Vc = 1024;
constexpr int BM = 64, BN = 128;
constexpr int MT = (Bc * Tc * Uc) / BM;  // 2048 blocks
constexpr int NT = Vc / BN;              // 8 n-tiles per block
constexpr int BDIM = 512;                // 8 waves

typedef __attribute__((ext_vector_type(8))) short short8;
typedef __attribute__((ext_vector_type(8))) unsigned short ushort8;
typedef __attribute__((ext_vector_type(4))) float f32x4;

__device__ inline unsigned short f2bf(float f) {
    union { float f; unsigned u; } v; v.f = f;
    unsigned r = v.u + 0x7FFFu + ((v.u >> 16) & 1u);  // RNE
    return (unsigned short)(r >> 16);
}

// ---- prep: W fp32 [V][D] -> bf16 [V][D] in d_ws ----
__global__ __launch_bounds__(256) void cvt_w(const float* __restrict__ W,
                                             unsigned short* __restrict__ Wb) {
    const int i = (blockIdx.x * 256 + threadIdx.x) * 8;  // 8 elems/thread
    const float4 a = *(const float4*)(W + i);
    const float4 b = *(const float4*)(W + i + 4);
    ushort8 v;
    v[0] = f2bf(a.x); v[1] = f2bf(a.y); v[2] = f2bf(a.z); v[3] = f2bf(a.w);
    v[4] = f2bf(b.x); v[5] = f2bf(b.y); v[6] = f2bf(b.z); v[7] = f2bf(b.w);
    *(ushort8*)(Wb + i) = v;
}

// ---- main kernel ----
__global__ __launch_bounds__(BDIM, 4) void joiner_v2(
    const float* __restrict__ x, const float* __restrict__ y,
    const unsigned short* __restrict__ Wb, const float* __restrict__ bias,
    float* __restrict__ out)
{
    __shared__ unsigned short As[BM * Dc];  // 64 KB, full-K A tile, swizzled

    const int tid  = threadIdx.x;
    const int lane = tid & 63;
    const int wid  = tid >> 6;
    const int wm = wid >> 2, wn = wid & 3;  // 2x4 wave grid, 32x32 tiles
    const int lr = lane & 15;
    const int l4 = lane >> 4;

    const int m0 = blockIdx.x * BM;
    const int bb = blockIdx.x / Tc;   // batch
    const int tt = blockIdx.x % Tc;   // time step (u = row index 0..63)

    // ---- Phase 1: stage A = relu(x[b,t,:]+y[b,u,:]) as bf16, XOR-swizzled ----
    // c = tid + i*512: u = c>>6, k-octet s = c&63. Wave-uniform u, coalesced k.
    const float* xrow = x + (size_t)(bb * Tc + tt) * Dc;
    #pragma unroll
    for (int i = 0; i < 8; ++i) {
        const int c = tid + i * BDIM;
        const int u = c >> 6;
        const int s = c & 63;
        const float4* xp = (const float4*)(xrow + s * 8);
        const float4* yp = (const float4*)(y + ((size_t)(bb * Uc + u) * Dc + s * 8));
        float4 xa = xp[0], xb = xp[1];
        float4 ya = yp[0], yb = yp[1];
        ushort8 hv;
        hv[0] = f2bf(fmaxf(xa.x + ya.x, 0.f));
        hv[1] = f2bf(fmaxf(xa.y + ya.y, 0.f));
        hv[2] = f2bf(fmaxf(xa.z + ya.z, 0.f));
        hv[3] = f2bf(fmaxf(xa.w + ya.w, 0.f));
        hv[4] = f2bf(fmaxf(xb.x + yb.x, 0.f));
        hv[5] = f2bf(fmaxf(xb.y + yb.y, 0.f));
        hv[6] = f2bf(fmaxf(xb.z + yb.z, 0.f));
        hv[7] = f2bf(fmaxf(xb.w + yb.w, 0.f));
        *(ushort8*)(&As[u * Dc + ((s ^ (u & 7)) * 8)]) = hv;
    }
    __syncthreads();  // the ONLY barrier

    // ---- Phase 2: loop n-tiles; W-frags streamed to regs, A-frags from LDS ----
    // B-frag (16x16x32): row v = lr, k-octet = l4. 16B contiguous in Wb[v][k].
    const unsigned short* wbase = Wb + (size_t)(wn * 32 + lr) * Dc + l4 * 8;

    for (int nt = 0; nt < NT; ++nt) {
        f32x4 acc[2][2] = {};  // wave tile 32x32: 2x2 frags of 16x16

        // bias for this wave's 32 columns
        const int vb = nt * BN + wn * 32 + lr;
        const float bv0 = bias[vb];
        const float bv1 = bias[vb + 16];

        short8 wbuf[2][4];  // [ping-pong][nf*2+kk]
        #pragma unroll
        for (int nf = 0; nf < 2; ++nf)
            #pragma unroll
            for (int kk = 0; kk < 2; ++kk)
                wbuf[0][nf * 2 + kk] = *(const short8*)(wbase + (size_t)(nt * BN + nf * 16) * Dc + kk * 32);

        #pragma unroll
        for (int ks = 0; ks < 8; ++ks) {
            // prefetch next k-step's W frags into the other buffer
            if (ks < 7) {
                #pragma unroll
                for (int nf = 0; nf < 2; ++nf)
                    #pragma unroll
                    for (int kk = 0; kk < 2; ++kk)
                        wbuf[(ks + 1) & 1][nf * 2 + kk] =
                            *(const short8*)(wbase + (size_t)(nt * BN + nf * 16) * Dc
                                             + (ks + 1) * 64 + kk * 32);
            }
            // A-frags from LDS (read-only, no barrier needed)
            short8 af[2][2];  // [kk][mf]
            #pragma unroll
            for (int mf = 0; mf < 2; ++mf) {
                const int r = wm * 32 + mf * 16 + lr;
                #pragma unroll
                for (int kk = 0; kk < 2; ++kk) {
                    const int o = ks * 8 + kk * 4 + l4;
                    af[kk][mf] = *(const short8*)(&As[r * Dc + ((o ^ (r & 7)) * 8)]);
                }
            }
            #pragma unroll
            for (int kk = 0; kk < 2; ++kk)
                #pragma unroll
                for (int mf = 0; mf < 2; ++mf)
                    #pragma unroll
                    for (int nf = 0; nf < 2; ++nf)
                        acc[mf][nf] = __builtin_amdgcn_mfma_f32_16x16x32_bf16(
                            af[kk][mf], wbuf[ks & 1][nf * 2 + kk], acc[mf][nf], 0, 0, 0);
        }

        // ---- epilogue for this n-tile: nf innermost -> adjacent half-lines ----
        #pragma unroll
        for (int mf = 0; mf < 2; ++mf) {
            const size_t rowbase = (size_t)(m0 + wm * 32 + mf * 16 + l4 * 4) * Vc;
            #pragma unroll
            for (int j = 0; j < 4; ++j) {
                const size_t rb = rowbase + (size_t)j * Vc + nt * BN + wn * 32 + lr;
                __builtin_nontemporal_store(acc[mf][0][j] + bv0, out + rb);
                __builtin_nontemporal_store(acc[mf][1][j] + bv1, out + rb + 16);
            }
        }
    }
}

// ---- round-1 fallback (used only if ws_size < 1MB) ----
constexpr int F_BM = 128, F_BN = 128, F_BK = 64;
constexpr int F_MT = (Bc * Tc * Uc) / F_BM;
constexpr int F_NT = Vc / F_BN;

__global__ __launch_bounds__(256) void joiner_mfma(
    const float* __restrict__ x, const float* __restrict__ y,
    const float* __restrict__ W, const float* __restrict__ bias,
    float* __restrict__ out)
{
    __shared__ unsigned short As[F_BM * F_BK];
    __shared__ unsigned short Ws[F_BN * F_BK];
    const int tid = threadIdx.x;
    const int mtile = blockIdx.x % F_MT;
    const int ntile = blockIdx.x / F_MT;
    const int m0 = mtile * F_BM, v0 = ntile * F_BN;
    const int bb = m0 / (Tc * Uc);
    const int t0 = (m0 % (Tc * Uc)) / Uc;
    const int lane = tid & 63, wid = tid >> 6;
    const int wm = wid >> 1, wn = wid & 1;
    const int lr = lane & 15, lk8 = lane >> 4;
    f32x4 acc[4][4] = {};
    for (int k0 = 0; k0 < Dc; k0 += F_BK) {
        __syncthreads();
        #pragma unroll
        for (int i = 0; i < 4; ++i) {
            const int chunk = tid + i * 256;
            const int row = chunk >> 3, slot = chunk & 7;
            const int ps8 = (slot ^ (row & 7)) * 8;
            const int t = t0 + (row >> 6), u = row & 63;
            const float4* xp = (const float4*)(x + ((size_t)(bb * Tc + t) * Dc + k0 + slot * 8));
            const float4* yp = (const float4*)(y + ((size_t)(bb * Uc + u) * Dc + k0 + slot * 8));
            float4 xa = xp[0], xb2 = xp[1], ya = yp[0], yb2 = yp[1];
            ushort8 hv;
            hv[0] = f2bf(fmaxf(xa.x + ya.x, 0.f)); hv[1] = f2bf(fmaxf(xa.y + ya.y, 0.f));
            hv[2] = f2bf(fmaxf(xa.z + ya.z, 0.f)); hv[3] = f2bf(fmaxf(xa.w + ya.w, 0.f));
            hv[4] = f2bf(fmaxf(xb2.x + yb2.x, 0.f)); hv[5] = f2bf(fmaxf(xb2.y + yb2.y, 0.f));
            hv[6] = f2bf(fmaxf(xb2.z + yb2.z, 0.f)); hv[7] = f2bf(fmaxf(xb2.w + yb2.w, 0.f));
            *(ushort8*)(&As[row * F_BK + ps8]) = hv;
            const float4* wp = (const float4*)(W + ((size_t)(v0 + row) * Dc + k0 + slot * 8));
            float4 wa = wp[0], wb2 = wp[1];
            ushort8 wv;
            wv[0] = f2bf(wa.x); wv[1] = f2bf(wa.y); wv[2] = f2bf(wa.z); wv[3] = f2bf(wa.w);
            wv[4] = f2bf(wb2.x); wv[5] = f2bf(wb2.y); wv[6] = f2bf(wb2.z); wv[7] = f2bf(wb2.w);
            *(ushort8*)(&Ws[row * F_BK + ps8]) = wv;
        }
        __syncthreads();
        #pragma unroll
        for (int kk = 0; kk < 2; ++kk) {
            const int psk = kk * 4 + lk8;
            short8 af[4], bfr[4];
            #pragma unroll
            for (int mf = 0; mf < 4; ++mf) {
                const int row = wm * 64 + mf * 16 + lr;
                af[mf] = *(const short8*)(&As[row * F_BK + ((psk ^ (row & 7)) * 8)]);
            }
            #pragma unroll
            for (int nf = 0; nf < 4; ++nf) {
                const int row = wn * 64 + nf * 16 + lr;
                bfr[nf] = *(const short8*)(&Ws[row * F_BK + ((psk ^ (row & 7)) * 8)]);
            }
            #pragma unroll
            for (int mf = 0; mf < 4; ++mf)
                #pragma unroll
                for (int nf = 0; nf < 4; ++nf)
                    acc[mf][nf] = __builtin_amdgcn_mfma_f32_16x16x32_bf16(af[mf], bfr[nf], acc[mf][nf], 0, 0, 0);
        }
    }
    #pragma unroll
    for (int nf = 0; nf < 4; ++nf) {
        const int v = v0 + wn * 64 + nf * 16 + lr;
        const float bv = bias[v];
        #pragma unroll
        for (int mf = 0; mf < 4; ++mf) {
            const int mrow = m0 + wm * 64 + mf * 16 + (lane >> 4) * 4;
            #pragma unroll
            for (int j = 0; j < 4; ++j)
                out[(size_t)(mrow + j) * Vc + v] = acc[mf][nf][j] + bv;
        }
    }
}

extern "C" void kernel_launch(void* const* d_in, const int* in_sizes, int n_in,
                              void* d_out, int out_size, void* d_ws, size_t ws_size,
                              hipStream_t stream) {
    const float* x = (const float*)d_in[0];
    const float* y = (const float*)d_in[1];
    const float* W = (const float*)d_in[2];
    const float* b = (const float*)d_in[3];
    float* out = (float*)d_out;

    const size_t w_bytes = (size_t)Vc * Dc * sizeof(unsigned short);  // 1 MB
    if (ws_size >= w_bytes) {
        unsigned short* Wb = (unsigned short*)d_ws;
        cvt_w<<<dim3((Vc * Dc) / (256 * 8)), 256, 0, stream>>>(W, Wb);
        joiner_v2<<<dim3(MT), BDIM, 0, stream>>>(x, y, Wb, b, out);
    } else {
        joiner_mfma<<<dim3(F_MT * F_NT), 256, 0, stream>>>(x, y, W, b, out);
    }
}

// Round 4
// 210.854 us; speedup vs baseline: 3.0635x; 3.0635x over previous
//
#include <hip/hip_runtime.h>
#include <hip/hip_bf16.h>

// RNN-T joiner: out[b,t,u,v] = sum_k relu(x[b,t,k]+y[b,u,k]) * W[v,k] + bias[v]
// GEMM: M=131072, N=1024, K=512; A generated on the fly.
//
// v3b (v3 + compile fix: nontemporal_store takes ext_vector f32x4, not float4):
// A staged once/block (64KB LDS, full K). W pre-converted to bf16 (d_ws),
// staged per (nt,kc) chunk [128 v x 64 k] via global_load_lds width=16 into a
// 4-buffer ring, distance-2 prefetch, counted vmcnt (never 0 mid-loop), raw
// s_barrier (1/step). W LDS is source-swizzled (linear DMA dest). Epilogue:
// per-wave LDS transpose -> f32x4 nontemporal stores (full 128B sectors).

constexpr int Bc = 8, Tc = 256, Uc = 64, Dc = 512, Vc = 1024;
constexpr int BM = 64, BN = 128;
constexpr int NT = Vc / BN;     // 8
constexpr int KC = Dc / 64;     // 8
constexpr int NSTEP = NT * KC;  // 64
constexpr int BDIM = 512;       // 8 waves, 2m x 4n, wave tile 32x32

typedef __attribute__((ext_vector_type(8))) short short8;
typedef __attribute__((ext_vector_type(8))) unsigned short ushort8;
typedef __attribute__((ext_vector_type(4))) float f32x4;

#define GLOAD16(g, l) __builtin_amdgcn_global_load_lds( \
    (const __attribute__((address_space(1))) unsigned int*)(g), \
    (__attribute__((address_space(3))) unsigned int*)(l), 16, 0, 0)

__device__ inline unsigned short f2bf(float f) {
    union { float f; unsigned u; } v; v.f = f;
    unsigned r = v.u + 0x7FFFu + ((v.u >> 16) & 1u);  // RNE
    return (unsigned short)(r >> 16);
}

// ---- prep: W fp32 [V][D] -> bf16 [V][D] in d_ws ----
__global__ __launch_bounds__(256) void cvt_w(const float* __restrict__ W,
                                             unsigned short* __restrict__ Wb) {
    const int i = (blockIdx.x * 256 + threadIdx.x) * 8;
    const float4 a = *(const float4*)(W + i);
    const float4 b = *(const float4*)(W + i + 4);
    ushort8 v;
    v[0] = f2bf(a.x); v[1] = f2bf(a.y); v[2] = f2bf(a.z); v[3] = f2bf(a.w);
    v[4] = f2bf(b.x); v[5] = f2bf(b.y); v[6] = f2bf(b.z); v[7] = f2bf(b.w);
    *(ushort8*)(Wb + i) = v;
}

__global__ __launch_bounds__(BDIM) void joiner_v3(
    const float* __restrict__ x, const float* __restrict__ y,
    const unsigned short* __restrict__ Wb, const float* __restrict__ bias,
    float* __restrict__ out)
{
    __shared__ unsigned short As[BM * Dc];       // 64 KB, swizzled, full K
    __shared__ unsigned short Ws[4][BN * 64];    // 64 KB ring (4 x 16KB)
    __shared__ float Tr[8][16 * 36];             // 18 KB per-wave transpose pad

    const int tid  = threadIdx.x;
    const int lane = tid & 63;
    const int wid  = tid >> 6;
    const int wm = wid >> 2, wn = wid & 3;  // 2x4 waves, 32x32 tiles
    const int lr = lane & 15;
    const int l4 = lane >> 4;

    const int m0 = blockIdx.x * BM;
    const int bb = blockIdx.x / Tc;
    const int tt = blockIdx.x % Tc;

    // ---- bias preload (all nt), then DRAIN so vmcnt queue = DMAs/stores only
    float bv0[NT], bv1[NT];
    #pragma unroll
    for (int nt = 0; nt < NT; ++nt) {
        bv0[nt] = bias[nt * BN + wn * 32 + lr];
        bv1[nt] = bias[nt * BN + wn * 32 + 16 + lr];
    }
    asm volatile("s_waitcnt vmcnt(0)" ::: "memory");
    __builtin_amdgcn_sched_barrier(0);

    // ---- prologue: issue W DMA for steps 0,1 (source-swizzled, linear dest)
    #pragma unroll
    for (int s = 0; s < 2; ++s) {
        #pragma unroll
        for (int i = 0; i < 2; ++i) {
            const int d  = i * BDIM + tid;       // chunk slot 0..1023
            const int rd = d >> 3, od = d & 7;
            const unsigned short* src =
                Wb + (size_t)rd * Dc + (s & 7) * 64 + ((od ^ (rd & 7)) * 8);
            GLOAD16(src, &Ws[s][d * 8]);
        }
    }

    // ---- phase 1: stage A = relu(x+y) bf16, XOR-swizzled ----
    const float* xrow = x + (size_t)(bb * Tc + tt) * Dc;
    #pragma unroll
    for (int i = 0; i < 8; ++i) {
        const int c = tid + i * BDIM;
        const int u = c >> 6;
        const int s = c & 63;
        const float4* xp = (const float4*)(xrow + s * 8);
        const float4* yp = (const float4*)(y + ((size_t)(bb * Uc + u) * Dc + s * 8));
        float4 xa = xp[0], xb = xp[1];
        float4 ya = yp[0], yb = yp[1];
        ushort8 hv;
        hv[0] = f2bf(fmaxf(xa.x + ya.x, 0.f));
        hv[1] = f2bf(fmaxf(xa.y + ya.y, 0.f));
        hv[2] = f2bf(fmaxf(xa.z + ya.z, 0.f));
        hv[3] = f2bf(fmaxf(xa.w + ya.w, 0.f));
        hv[4] = f2bf(fmaxf(xb.x + yb.x, 0.f));
        hv[5] = f2bf(fmaxf(xb.y + yb.y, 0.f));
        hv[6] = f2bf(fmaxf(xb.z + yb.z, 0.f));
        hv[7] = f2bf(fmaxf(xb.w + yb.w, 0.f));
        *(ushort8*)(&As[u * Dc + ((s ^ (u & 7)) * 8)]) = hv;
    }
    asm volatile("s_waitcnt lgkmcnt(0)" ::: "memory");
    __builtin_amdgcn_s_barrier();   // As visible to all waves

    // ---- main loop: 64 steps, fully unrolled ----
    #pragma unroll
    for (int nt = 0; nt < NT; ++nt) {
        f32x4 acc[2][2] = {};
        #pragma unroll
        for (int kc = 0; kc < KC; ++kc) {
            const int s = nt * KC + kc;
            // issue prefetch for step s+2 (distance-2: buffer last read at s-2,
            // all waves passed barrier(s-1) before this issue -> race-free)
            if (s + 2 < NSTEP) {
                const int sn  = s + 2;
                const int ntn = sn >> 3, kcn = sn & 7;
                #pragma unroll
                for (int i = 0; i < 2; ++i) {
                    const int d  = i * BDIM + tid;
                    const int rd = d >> 3, od = d & 7;
                    const unsigned short* src =
                        Wb + (size_t)(ntn * BN + rd) * Dc + kcn * 64 + ((od ^ (rd & 7)) * 8);
                    GLOAD16(src, &Ws[sn & 3][d * 8]);
                }
            }
            // counted wait: buf s (2 oldest DMAs) must be done.
            // after an epilogue, 4 stores sit between buf_s and the newest DMA
            // -> vmcnt(8) skips waiting on them; normally vmcnt(4).
            if (s == NSTEP - 1)            asm volatile("s_waitcnt vmcnt(0)" ::: "memory");
            else if (s == NSTEP - 2)       asm volatile("s_waitcnt vmcnt(2)" ::: "memory");
            else if (s >= 8 && (s & 7) < 2) asm volatile("s_waitcnt vmcnt(8)" ::: "memory");
            else                           asm volatile("s_waitcnt vmcnt(4)" ::: "memory");
            __builtin_amdgcn_s_barrier();
            __builtin_amdgcn_sched_barrier(0);

            // fragments
            const unsigned short* wsb = &Ws[s & 3][0];
            short8 af[2][2], wf[2][2];
            #pragma unroll
            for (int kk = 0; kk < 2; ++kk) {
                const int oA = kc * 8 + kk * 4 + l4;  // A octet 0..63
                #pragma unroll
                for (int mf = 0; mf < 2; ++mf) {
                    const int r = wm * 32 + mf * 16 + lr;
                    af[kk][mf] = *(const short8*)(&As[r * Dc + ((oA ^ (r & 7)) * 8)]);
                }
                const int oW = kk * 4 + l4;           // W octet 0..7
                #pragma unroll
                for (int nf = 0; nf < 2; ++nf) {
                    const int vr = wn * 32 + nf * 16 + lr;
                    wf[kk][nf] = *(const short8*)(wsb + vr * 64 + ((oW ^ (vr & 7)) * 8));
                }
            }
            #pragma unroll
            for (int kk = 0; kk < 2; ++kk)
                #pragma unroll
                for (int mf = 0; mf < 2; ++mf)
                    #pragma unroll
                    for (int nf = 0; nf < 2; ++nf)
                        acc[mf][nf] = __builtin_amdgcn_mfma_f32_16x16x32_bf16(
                            af[kk][mf], wf[kk][nf], acc[mf][nf], 0, 0, 0);
        }

        // ---- epilogue nt: per-wave LDS transpose -> full-128B f32x4 stores
        float* tr = &Tr[wid][0];  // 16 rows x stride 36 (conflict-free, 16B-aligned)
        #pragma unroll
        for (int mf = 0; mf < 2; ++mf) {
            #pragma unroll
            for (int nf = 0; nf < 2; ++nf)
                #pragma unroll
                for (int j = 0; j < 4; ++j)
                    tr[(l4 * 4 + j) * 36 + nf * 16 + lr] =
                        acc[mf][nf][j] + (nf ? bv1[nt] : bv0[nt]);
            #pragma unroll
            for (int h = 0; h < 2; ++h) {
                const int rr = h * 8 + (lane >> 3);
                const int c4 = (lane & 7) * 4;
                f32x4 o;
                o[0] = tr[rr * 36 + c4 + 0];
                o[1] = tr[rr * 36 + c4 + 1];
                o[2] = tr[rr * 36 + c4 + 2];
                o[3] = tr[rr * 36 + c4 + 3];
                const size_t off = (size_t)(m0 + wm * 32 + mf * 16 + rr) * Vc
                                   + nt * BN + wn * 32 + c4;
                __builtin_nontemporal_store(o, (f32x4*)(out + off));
            }
        }
    }
}

// ---- round-1 fallback (only if ws_size < 1MB) ----
constexpr int F_BM = 128, F_BN = 128, F_BK = 64;
constexpr int F_MT = (Bc * Tc * Uc) / F_BM;
constexpr int F_NT = Vc / F_BN;

__global__ __launch_bounds__(256) void joiner_mfma(
    const float* __restrict__ x, const float* __restrict__ y,
    const float* __restrict__ W, const float* __restrict__ bias,
    float* __restrict__ out)
{
    __shared__ unsigned short As[F_BM * F_BK];
    __shared__ unsigned short Wsh[F_BN * F_BK];
    const int tid = threadIdx.x;
    const int mtile = blockIdx.x % F_MT;
    const int ntile = blockIdx.x / F_MT;
    const int m0 = mtile * F_BM, v0 = ntile * F_BN;
    const int bb = m0 / (Tc * Uc);
    const int t0 = (m0 % (Tc * Uc)) / Uc;
    const int lane = tid & 63, wid = tid >> 6;
    const int wm = wid >> 1, wn = wid & 1;
    const int lr = lane & 15, lk8 = lane >> 4;
    f32x4 acc[4][4] = {};
    for (int k0 = 0; k0 < Dc; k0 += F_BK) {
        __syncthreads();
        #pragma unroll
        for (int i = 0; i < 4; ++i) {
            const int chunk = tid + i * 256;
            const int row = chunk >> 3, slot = chunk & 7;
            const int ps8 = (slot ^ (row & 7)) * 8;
            const int t = t0 + (row >> 6), u = row & 63;
            const float4* xp = (const float4*)(x + ((size_t)(bb * Tc + t) * Dc + k0 + slot * 8));
            const float4* yp = (const float4*)(y + ((size_t)(bb * Uc + u) * Dc + k0 + slot * 8));
            float4 xa = xp[0], xb2 = xp[1], ya = yp[0], yb2 = yp[1];
            ushort8 hv;
            hv[0] = f2bf(fmaxf(xa.x + ya.x, 0.f)); hv[1] = f2bf(fmaxf(xa.y + ya.y, 0.f));
            hv[2] = f2bf(fmaxf(xa.z + ya.z, 0.f)); hv[3] = f2bf(fmaxf(xa.w + ya.w, 0.f));
            hv[4] = f2bf(fmaxf(xb2.x + yb2.x, 0.f)); hv[5] = f2bf(fmaxf(xb2.y + yb2.y, 0.f));
            hv[6] = f2bf(fmaxf(xb2.z + yb2.z, 0.f)); hv[7] = f2bf(fmaxf(xb2.w + yb2.w, 0.f));
            *(ushort8*)(&As[row * F_BK + ps8]) = hv;
            const float4* wp = (const float4*)(W + ((size_t)(v0 + row) * Dc + k0 + slot * 8));
            float4 wa = wp[0], wb2 = wp[1];
            ushort8 wv;
            wv[0] = f2bf(wa.x); wv[1] = f2bf(wa.y); wv[2] = f2bf(wa.z); wv[3] = f2bf(wa.w);
            wv[4] = f2bf(wb2.x); wv[5] = f2bf(wb2.y); wv[6] = f2bf(wb2.z); wv[7] = f2bf(wb2.w);
            *(ushort8*)(&Wsh[row * F_BK + ps8]) = wv;
        }
        __syncthreads();
        #pragma unroll
        for (int kk = 0; kk < 2; ++kk) {
            const int psk = kk * 4 + lk8;
            short8 af[4], bfr[4];
            #pragma unroll
            for (int mf = 0; mf < 4; ++mf) {
                const int row = wm * 64 + mf * 16 + lr;
                af[mf] = *(const short8*)(&As[row * F_BK + ((psk ^ (row & 7)) * 8)]);
            }
            #pragma unroll
            for (int nf = 0; nf < 4; ++nf) {
                const int row = wn * 64 + nf * 16 + lr;
                bfr[nf] = *(const short8*)(&Wsh[row * F_BK + ((psk ^ (row & 7)) * 8)]);
            }
            #pragma unroll
            for (int mf = 0; mf < 4; ++mf)
                #pragma unroll
                for (int nf = 0; nf < 4; ++nf)
                    acc[mf][nf] = __builtin_amdgcn_mfma_f32_16x16x32_bf16(af[mf], bfr[nf], acc[mf][nf], 0, 0, 0);
        }
    }
    #pragma unroll
    for (int nf = 0; nf < 4; ++nf) {
        const int v = v0 + wn * 64 + nf * 16 + lr;
        const float bv = bias[v];
        #pragma unroll
        for (int mf = 0; mf < 4; ++mf) {
            const int mrow = m0 + wm * 64 + mf * 16 + (lane >> 4) * 4;
            #pragma unroll
            for (int j = 0; j < 4; ++j)
                out[(size_t)(mrow + j) * Vc + v] = acc[mf][nf][j] + bv;
        }
    }
}

extern "C" void kernel_launch(void* const* d_in, const int* in_sizes, int n_in,
                              void* d_out, int out_size, void* d_ws, size_t ws_size,
                              hipStream_t stream) {
    const float* x = (const float*)d_in[0];
    const float* y = (const float*)d_in[1];
    const float* W = (const float*)d_in[2];
    const float* b = (const float*)d_in[3];
    float* out = (float*)d_out;

    const size_t w_bytes = (size_t)Vc * Dc * sizeof(unsigned short);  // 1 MB
    if (ws_size >= w_bytes) {
        unsigned short* Wb = (unsigned short*)d_ws;
        cvt_w<<<dim3((Vc * Dc) / (256 * 8)), 256, 0, stream>>>(W, Wb);
        joiner_v3<<<dim3(Bc * Tc), BDIM, 0, stream>>>(x, y, Wb, b, out);
    } else {
        joiner_mfma<<<dim3(F_MT * F_NT), 256, 0, stream>>>(x, y, W, b, out);
    }
}